// Round 15
// baseline (261.836 us; speedup 1.0000x reference)
//
#include <hip/hip_runtime.h>
#include <cstdint>
#include <cstddef>
#include <utility>
#include <type_traits>

#define PI_F 3.14159265358979323846f

typedef __attribute__((ext_vector_type(8))) _Float16 half8;
typedef __attribute__((ext_vector_type(4))) float f32x4;

struct U4 { unsigned int w[4]; };

static __device__ __forceinline__ unsigned int packhalf2(float c, float s) {
  _Float16 hc = (_Float16)c, hs = (_Float16)s;
  unsigned short uc = __builtin_bit_cast(unsigned short, hc);
  unsigned short us = __builtin_bit_cast(unsigned short, hs);
  return (unsigned int)uc | ((unsigned int)us << 16);
}

// ---------------------------------------------------------------------------
// K1: MLP for all 2B samples -> hz[sample][16] = {h[0..7], z[0..6], 0}.
// Block 0 thread 0 also zero-inits scalars + out.
// ---------------------------------------------------------------------------
__global__ __launch_bounds__(256) void k_mlp(
    const float* __restrict__ x1, const float* __restrict__ x0,
    const float* __restrict__ W1, const float* __restrict__ b1,
    const float* __restrict__ W2, const float* __restrict__ b2,
    const float* __restrict__ W3, const float* __restrict__ b3,
    float* __restrict__ hz, int B, float* __restrict__ scalars,
    float* __restrict__ out) {
  int s = blockIdx.x * blockDim.x + threadIdx.x;
  if (blockIdx.x == 0 && threadIdx.x == 0) {
    scalars[0] = 0.f;
    scalars[1] = 0.f;
    out[0] = 0.f;
  }
  if (s >= 2 * B) return;
  const float* xp = (s < B) ? (x1 + (size_t)s * 8) : (x0 + (size_t)(s - B) * 8);
  float x[8];
#pragma unroll
  for (int k = 0; k < 8; k++) x[k] = xp[k];
  float a1[10];
#pragma unroll
  for (int o = 0; o < 10; o++) {
    float v = b1[o];
#pragma unroll
    for (int k = 0; k < 8; k++) v = fmaf(W1[o * 8 + k], x[k], v);
    a1[o] = fmaxf(v, 0.f);
  }
  float a2[10];
#pragma unroll
  for (int o = 0; o < 10; o++) {
    float v = b2[o];
#pragma unroll
    for (int k = 0; k < 10; k++) v = fmaf(W2[o * 10 + k], a1[k], v);
    a2[o] = fmaxf(v, 0.f);
  }
  float h[8];
#pragma unroll
  for (int o = 0; o < 8; o++) {
    float v = b3[o];
#pragma unroll
    for (int k = 0; k < 10; k++) v = fmaf(W3[o * 10 + k], a2[k], v);
    h[o] = v;
  }
  float outv[16];
#pragma unroll
  for (int k = 0; k < 8; k++) outv[k] = h[k];
#pragma unroll
  for (int k = 0; k < 7; k++) outv[8 + k] = (PI_F - h[k]) * (PI_F - h[k + 1]);
  outv[15] = 0.f;
  float4* dst = (float4*)(hz + (size_t)s * 16);
#pragma unroll
  for (int q = 0; q < 4; q++) dst[q] = ((float4*)outv)[q];
}

// ---------------------------------------------------------------------------
// K3: FUSED gen+GEMM with gen/MFMA INTERLEAVE (R14 was serial-per-wave:
// VALUBusy 65 + MfmaUtil 28 summed to ~93 -> pipes not overlapped). Now:
// MFMA(kk0) -> genA(next) -> MFMA(kk1) -> genB(next), setprio(1) around
// MFMA clusters (T5). Gen math/layout identical to R14 (proven).
// Quadrants as R14: qt0 [0,128) diag kbPer=32; qt1 [128,384) off kbPer=16;
// qt2 [384,512) diag. Gray-walk indices kept compile-time via template NJ.
// ---------------------------------------------------------------------------
__global__ __launch_bounds__(512) void k_gemm_f(const float* __restrict__ hz,
                                                float* __restrict__ P) {
  __shared__ _Float16 lds[2][16384];  // 2 x 32 KB chunk buffers
  __shared__ float hzb[2][32][17];    // double-buffered hz rows (padded)
  int b = blockIdx.x;
  int qt = (b < 128) ? 0 : (b < 384 ? 1 : 2);
  int z = b - ((qt == 0) ? 0 : (qt == 1) ? 128 : 384);
  int kbPer = (qt == 1) ? 16 : 32;
  int kb0 = z * kbPer;
  int rowLocalBase = (qt == 2) ? 128 : 0;
  int bRowBase = (qt == 1) ? 128 : 0;
  int t = threadIdx.x, wave = t >> 6, lane = t & 63;
  unsigned int reMask = (kb0 < 2048) ? 0u : 0x80008000u;
  unsigned int imMask = (kb0 < 2048) ? 0x80000000u : 0x00008000u;

  int s = t & 31, octH = t >> 5;
  int oct = octH & 7, jHalf = octH >> 3;
  const int halfoff = (2 * s) ^ (oct << 3);
  const float S5 = (oct & 4) ? -1.f : 1.f;
  const float S6 = (oct & 2) ? -1.f : 1.f;
  const float S7 = (oct & 1) ? -1.f : 1.f;

  auto loadHz = [&](int kb) {
    if (t < 128) {
      int smp = t >> 2, q = t & 3;
      const float4 v =
          *(const float4*)(hz + (size_t)(kb * 32 + smp) * 16 + q * 4);
      float* d = &hzb[kb & 1][smp][q * 4];
      d[0] = v.x;
      d[1] = v.y;
      d[2] = v.z;
      d[3] = v.w;
    }
  };

  f32x4 accR[2][4] = {};
  f32x4 accI[2][4] = {};

  auto mfmaKK = [&](int kk, int buf) {
    int cb = kk * 4 + (lane >> 4);
    half8 af[2];
#pragma unroll
    for (int fr = 0; fr < 2; fr++) {
      int r = (wave >> 1) * 32 + fr * 16 + (lane & 15);
      af[fr] = *(const half8*)&lds[buf][r * 64 + ((cb ^ (r & 7)) << 3)];
    }
#pragma unroll
    for (int fc = 0; fc < 4; fc++) {
      int rb = bRowBase + (wave & 1) * 64 + fc * 16 + (lane & 15);
      half8 bv = *(const half8*)&lds[buf][rb * 64 + ((cb ^ (rb & 7)) << 3)];
      U4 u = __builtin_bit_cast(U4, bv), ur, ui;
#pragma unroll
      for (int q = 0; q < 4; q++) {
        unsigned int xv = u.w[q];
        ur.w[q] = xv ^ reMask;
        ui.w[q] = ((xv << 16) | (xv >> 16)) ^ imMask;
      }
      half8 bfr = __builtin_bit_cast(half8, ur);
      half8 bfi = __builtin_bit_cast(half8, ui);
#pragma unroll
      for (int fr = 0; fr < 2; fr++) {
        accR[fr][fc] = __builtin_amdgcn_mfma_f32_16x16x32_f16(
            af[fr], bfr, accR[fr][fc], 0, 0, 0);
        accI[fr][fc] = __builtin_amdgcn_mfma_f32_16x16x32_f16(
            af[fr], bfi, accI[fr][fc], 0, 0, 0);
      }
    }
  };

  auto runLoop = [&](auto njc) {
    constexpr int NJ = decltype(njc)::value;
    constexpr int NH = NJ / 2;
    const int jj0 = (NJ == 16) ? jHalf * 16
                               : ((qt == 2) ? 16 : 0) + jHalf * 8;
    float h[8], z7[7], sg[5], phi;
    int g;
    auto initGen = [&](int kb) {
      int hb = kb & 1;
#pragma unroll
      for (int k = 0; k < 8; k++) h[k] = hzb[hb][s][k];
#pragma unroll
      for (int k = 0; k < 7; k++) z7[k] = hzb[hb][s][8 + k];
      int g0 = jj0 ^ (jj0 >> 1);
#pragma unroll
      for (int w = 0; w < 5; w++) sg[w] = ((g0 >> (4 - w)) & 1) ? -1.f : 1.f;
      phi = sg[0] * h[0] + sg[1] * h[1] + sg[2] * h[2] + sg[3] * h[3] +
            sg[4] * h[4] + S5 * h[5] + S6 * h[6] + S7 * h[7] +
            sg[0] * sg[1] * z7[0] + sg[1] * sg[2] * z7[1] +
            sg[2] * sg[3] * z7[2] + sg[3] * sg[4] * z7[3] +
            sg[4] * S5 * z7[4] + S5 * S6 * z7[5] + S6 * S7 * z7[6];
      g = g0;
    };
    auto emitRow = [&](int buf) {
      int lr = g * 8 + oct - rowLocalBase;
      float r = phi * 0.07957747154594767f;  // phi/(4*pi) revolutions
      r = r - floorf(r);
      float sv = __builtin_amdgcn_sinf(r);
      float cv = __builtin_amdgcn_cosf(r);
      *(unsigned int*)&lds[buf][lr * 64 + halfoff] = packhalf2(cv, sv);
    };
#define GSTEP(stp)                                             \
  {                                                            \
    const int bbit = __builtin_ctz(stp);                       \
    const int w = 4 - bbit;                                    \
    float nbl = (w == 0) ? 0.f : sg[w - 1] * z7[w - 1];        \
    float nbr = (w == 4) ? S5 * z7[4] : sg[w + 1] * z7[w];     \
    phi -= 2.f * sg[w] * (h[w] + nbl + nbr);                   \
    sg[w] = -sg[w];                                            \
    g ^= (1 << bbit);                                          \
  }
    auto genA = [&](int buf) {  // first half: emit g0 + steps 1..NH-1
      emitRow(buf);
#pragma unroll
      for (int stp = 1; stp < NH; stp++) {
        GSTEP(stp);
        emitRow(buf);
      }
    };
    auto genB = [&](int buf) {  // second half: steps NH..NJ-1
#pragma unroll
      for (int stp = NH; stp < NJ; stp++) {
        GSTEP(stp);
        emitRow(buf);
      }
    };
#undef GSTEP

    // prologue: hz(kb0) -> gen chunk kb0 -> hz(kb0+1)
    loadHz(kb0);
    __syncthreads();
    initGen(kb0);
    genA(0);
    genB(0);
    loadHz(kb0 + 1);
    __syncthreads();

    for (int it = 0; it < kbPer; ++it) {
      int buf = it & 1, nb = buf ^ 1;
      bool hasNext = (it + 1 < kbPer);
      if (hasNext) initGen(kb0 + it + 1);
      __builtin_amdgcn_s_setprio(1);
      mfmaKK(0, buf);
      __builtin_amdgcn_s_setprio(0);
      if (hasNext) genA(nb);
      __builtin_amdgcn_s_setprio(1);
      mfmaKK(1, buf);
      __builtin_amdgcn_s_setprio(0);
      if (hasNext) {
        genB(nb);
        if (it + 2 < kbPer) loadHz(kb0 + it + 2);
      }
      __syncthreads();  // gen(it+1) writes + MFMA(it) reads complete
    }
  };

  if (qt == 1)
    runLoop(std::integral_constant<int, 16>{});
  else
    runLoop(std::integral_constant<int, 8>{});

  float* PR = P + (size_t)b * 32768;
  float* PI = PR + 16384;
  int r4 = (lane >> 4) * 4, cj = lane & 15;
#pragma unroll
  for (int fr = 0; fr < 2; fr++)
#pragma unroll
    for (int fc = 0; fc < 4; fc++)
#pragma unroll
      for (int r = 0; r < 4; r++) {
        int li = (wave >> 1) * 32 + fr * 16 + r4 + r;
        int lj = (wave & 1) * 64 + fc * 16 + cj;
        PR[li * 128 + lj] = accR[fr][fc][r];
        PI[li * 128 + lj] = accI[fr][fc][r];
      }
}

// ---------------------------------------------------------------------------
// K4a: stage-1 reduce over slab groups. grid (128 rows, 3 qts, 8 groups).
// ---------------------------------------------------------------------------
__global__ __launch_bounds__(128) void k_reduce1(const float* __restrict__ P,
                                                 float* __restrict__ Q) {
  int r = blockIdx.x, qt = blockIdx.y, g = blockIdx.z, c = threadIdx.x;
  int nsl = (qt == 1) ? 32 : 16;
  int b0 = ((qt == 0) ? 0 : (qt == 1) ? 128 : 384) + g * nsl;
  float vR = 0.f, vI = 0.f;
  for (int u = 0; u < nsl; u++) {
    const float* base = P + (size_t)(b0 + u) * 32768 + r * 128 + c;
    vR += base[0];
    vI += base[16384];
  }
  size_t qidx = ((size_t)(g * 3 + qt) * 128 + r) * 128 + c;
  Q[qidx] = vR;
  Q[qidx + (size_t)8 * 3 * 16384] = vI;
}

// K4b: stage-2: sum 8 groups, map quadrant->global, Hermitian A + ||A||_F^2.
__global__ __launch_bounds__(128) void k_reduce2(const float* __restrict__ Q,
                                                 float* __restrict__ AR,
                                                 float* __restrict__ AI,
                                                 float* __restrict__ sumsq,
                                                 float scale) {
  int r = blockIdx.x, qt = blockIdx.y, c = threadIdx.x;
  float vR = 0.f, vI = 0.f;
#pragma unroll
  for (int g = 0; g < 8; g++) {
    size_t qidx = ((size_t)(g * 3 + qt) * 128 + r) * 128 + c;
    vR += Q[qidx];
    vI += Q[qidx + (size_t)8 * 3 * 16384];
  }
  vR *= scale;
  vI *= scale;
  int i = (qt == 2) ? 128 + r : r;
  int j = (qt == 0) ? c : 128 + c;
  float ss = 0.f;
  bool diagQ = (qt != 1);
  if (!diagQ || c > r) {
    AR[i * 256 + j] = vR;
    AR[j * 256 + i] = vR;
    AI[i * 256 + j] = vI;
    AI[j * 256 + i] = -vI;
    ss = 2.f * (vR * vR + vI * vI);
  } else if (c == r) {
    AR[i * 256 + j] = vR;
    AI[i * 256 + j] = 0.f;
    ss = vR * vR;
  }
#pragma unroll
  for (int o = 32; o > 0; o >>= 1) ss += __shfl_down(ss, o);
  __shared__ float w2[2];
  if ((c & 63) == 0) w2[c >> 6] = ss;
  __syncthreads();
  if (c == 0) atomicAdd(sumsq, w2[0] + w2[1]);
}

// ---------------------------------------------------------------------------
// Triangle unrank: block k -> (bi, bj), bi >= bj. All NS iterates are
// Hermitian (X and X^2 commute -> X@X^2 Hermitian), so compute only the
// lower-triangle 16x16-tile blocks (136 of 256) and mirror conj-transpose.
// ---------------------------------------------------------------------------
static __device__ __forceinline__ void unrank(int k, int& bi, int& bj) {
  bi = (int)((sqrtf(8.f * (float)k + 1.f) - 1.f) * 0.5f);
  if ((bi + 1) * (bi + 2) / 2 <= k) bi++;
  if (bi * (bi + 1) / 2 > k) bi--;
  bj = k - bi * (bi + 1) / 2;
}

// Newton-Schulz matmuls, k-split-4 inner loop (R9/R13-proven — frozen).
__global__ __launch_bounds__(1024) void k_csq(
    const float* __restrict__ XR, const float* __restrict__ XI,
    float* __restrict__ YR, float* __restrict__ YI,
    float* __restrict__ sumsqY, int accumNorm) {
  __shared__ float rp[16][258][2];
  __shared__ float cpT[16][258][2];
  __shared__ float pacc[3][256][2];
  __shared__ float w16[16];
  int t = threadIdx.x;
  int bi, bj;
  unrank(blockIdx.x, bi, bj);
  {
    int r = t >> 6, c = (t & 63) * 4;
    const float4 vr = *(const float4*)&XR[(bi * 16 + r) * 256 + c];
    const float4 vi = *(const float4*)&XI[(bi * 16 + r) * 256 + c];
    float4 p0 = {vr.x, vi.x, vr.y, vi.y};
    float4 p1 = {vr.z, vi.z, vr.w, vi.w};
    *(float4*)&rp[r][c][0] = p0;
    *(float4*)&rp[r][c + 2][0] = p1;
    int row = t >> 2, c0 = (t & 3) * 4;
    const float4 wr = *(const float4*)&XR[row * 256 + bj * 16 + c0];
    const float4 wi = *(const float4*)&XI[row * 256 + bj * 16 + c0];
    float2 q0 = {wr.x, wi.x}, q1 = {wr.y, wi.y};
    float2 q2 = {wr.z, wi.z}, q3 = {wr.w, wi.w};
    *(float2*)&cpT[c0 + 0][row][0] = q0;
    *(float2*)&cpT[c0 + 1][row][0] = q1;
    *(float2*)&cpT[c0 + 2][row][0] = q2;
    *(float2*)&cpT[c0 + 3][row][0] = q3;
  }
  __syncthreads();
  int sub = t >> 8, tt = t & 255, ty = tt >> 4, tx = tt & 15;
  float sR = 0.f, sI = 0.f;
  int k0 = sub * 64;
#pragma unroll 8
  for (int k = k0; k < k0 + 64; k++) {
    float xr = rp[ty][k][0], xi = rp[ty][k][1];
    float yr = cpT[tx][k][0], yi = cpT[tx][k][1];
    sR = fmaf(xr, yr, sR);
    sR = fmaf(-xi, yi, sR);
    sI = fmaf(xr, yi, sI);
    sI = fmaf(xi, yr, sI);
  }
  if (sub) {
    pacc[sub - 1][tt][0] = sR;
    pacc[sub - 1][tt][1] = sI;
  }
  __syncthreads();
  float v = 0.f;
  if (sub == 0) {
    sR += (pacc[0][tt][0] + pacc[1][tt][0]) + pacc[2][tt][0];
    sI += (pacc[0][tt][1] + pacc[1][tt][1]) + pacc[2][tt][1];
    int i = bi * 16 + ty, j = bj * 16 + tx;
    YR[i * 256 + j] = sR;
    YI[i * 256 + j] = sI;
    if (bi != bj) {  // mirror conj-transpose tile
      YR[j * 256 + i] = sR;
      YI[j * 256 + i] = -sI;
    }
    if (accumNorm) {
      float wgt = (bi == bj) ? 1.f : 2.f;
      v = wgt * (sR * sR + sI * sI);
    }
  }
#pragma unroll
  for (int o = 32; o > 0; o >>= 1) v += __shfl_down(v, o);
  if ((t & 63) == 0) w16[t >> 6] = v;
  __syncthreads();
  if (t == 0 && accumNorm)
    atomicAdd(sumsqY, (w16[0] + w16[1]) + (w16[2] + w16[3]));
}

// Z = aC*X - bC*(X@Y); triangular + mirror. mode 0: raw-A norm-folded
// 1.5-NS; mode 1: 2x-x^3; mode 2: 1.5-NS. finalTrace: out += -0.5*w*sum.
__global__ __launch_bounds__(1024) void k_cupd(
    const float* __restrict__ XR, const float* __restrict__ XI,
    const float* __restrict__ YR, const float* __restrict__ YI,
    float* __restrict__ ZR, float* __restrict__ ZI,
    const float* __restrict__ scalars, int mode,
    const float* __restrict__ AR, const float* __restrict__ AI,
    float* __restrict__ out, int finalTrace) {
  __shared__ float rp[16][258][2];
  __shared__ float cpT[16][258][2];
  __shared__ float pacc[3][256][2];
  __shared__ float w16[16];
  int t = threadIdx.x;
  int bi, bj;
  unrank(blockIdx.x, bi, bj);
  {
    int r = t >> 6, c = (t & 63) * 4;
    const float4 vr = *(const float4*)&XR[(bi * 16 + r) * 256 + c];
    const float4 vi = *(const float4*)&XI[(bi * 16 + r) * 256 + c];
    float4 p0 = {vr.x, vi.x, vr.y, vi.y};
    float4 p1 = {vr.z, vi.z, vr.w, vi.w};
    *(float4*)&rp[r][c][0] = p0;
    *(float4*)&rp[r][c + 2][0] = p1;
    int row = t >> 2, c0 = (t & 3) * 4;
    const float4 wr = *(const float4*)&YR[row * 256 + bj * 16 + c0];
    const float4 wi = *(const float4*)&YI[row * 256 + bj * 16 + c0];
    float2 q0 = {wr.x, wi.x}, q1 = {wr.y, wi.y};
    float2 q2 = {wr.z, wi.z}, q3 = {wr.w, wi.w};
    *(float2*)&cpT[c0 + 0][row][0] = q0;
    *(float2*)&cpT[c0 + 1][row][0] = q1;
    *(float2*)&cpT[c0 + 2][row][0] = q2;
    *(float2*)&cpT[c0 + 3][row][0] = q3;
  }
  __syncthreads();
  int sub = t >> 8, tt = t & 255, ty = tt >> 4, tx = tt & 15;
  float sR = 0.f, sI = 0.f;
  int k0 = sub * 64;
#pragma unroll 8
  for (int k = k0; k < k0 + 64; k++) {
    float xr = rp[ty][k][0], xi = rp[ty][k][1];
    float yr = cpT[tx][k][0], yi = cpT[tx][k][1];
    sR = fmaf(xr, yr, sR);
    sR = fmaf(-xi, yi, sR);
    sI = fmaf(xr, yi, sI);
    sI = fmaf(xi, yr, sI);
  }
  if (sub) {
    pacc[sub - 1][tt][0] = sR;
    pacc[sub - 1][tt][1] = sI;
  }
  __syncthreads();
  float v = 0.f;
  if (sub == 0) {
    sR += (pacc[0][tt][0] + pacc[1][tt][0]) + pacc[2][tt][0];
    sI += (pacc[0][tt][1] + pacc[1][tt][1]) + pacc[2][tt][1];
    float aC, bC;
    if (mode == 0) {
      float f2 = scalars[0];
      float f = sqrtf(f2);
      float Rhat = 1.41421356f * sqrtf(scalars[1]) / f2;
      float g = 1.0f / (1.75f * Rhat);
      aC = 1.5f * g / f;
      float gf = g / f;
      bC = 0.5f * gf * gf * gf;
    } else if (mode == 1) {
      aC = 2.0f;
      bC = 1.0f;
    } else {
      aC = 1.5f;
      bC = 0.5f;
    }
    int idx = (bi * 16 + ty) * 256 + bj * 16 + tx;
    float zr = aC * XR[idx] - bC * sR;
    float zi = aC * XI[idx] - bC * sI;
    if (!finalTrace) {
      ZR[idx] = zr;
      ZI[idx] = zi;
      if (bi != bj) {
        ZR[(bj * 16 + tx) * 256 + bi * 16 + ty] = zr;
        ZI[(bj * 16 + tx) * 256 + bi * 16 + ty] = -zi;
      }
    } else {
      float wgt = (bi == bj) ? 1.f : 2.f;
      v = wgt * (AR[idx] * zr + AI[idx] * zi);
    }
  }
#pragma unroll
  for (int o = 32; o > 0; o >>= 1) v += __shfl_down(v, o);
  if ((t & 63) == 0) w16[t >> 6] = v;
  __syncthreads();
  if (t == 0 && finalTrace)
    atomicAdd(out, -0.5f * ((w16[0] + w16[1]) + (w16[2] + w16[3])));
}

// ---------------------------------------------------------------------------
extern "C" void kernel_launch(void* const* d_in, const int* in_sizes, int n_in,
                              void* d_out, int out_size, void* d_ws,
                              size_t ws_size, hipStream_t stream) {
  const float* x1 = (const float*)d_in[0];
  const float* x0 = (const float*)d_in[1];
  const float* W1 = (const float*)d_in[2];
  const float* b1 = (const float*)d_in[3];
  const float* W2 = (const float*)d_in[4];
  const float* b2 = (const float*)d_in[5];
  const float* W3 = (const float*)d_in[6];
  const float* b3 = (const float*)d_in[7];
  (void)n_in;
  (void)out_size;
  (void)ws_size;

  const int B = in_sizes[0] / 8;  // 65536
  const int total = 2 * B;        // 131072

  char* ws = (char*)d_ws;
  size_t off = 0;
  auto carve = [&](size_t bytes) -> void* {
    off = (off + 255) & ~(size_t)255;
    void* p = ws + off;
    off += bytes;
    return p;
  };
  float* hz = (float*)carve((size_t)total * 16 * 4);        // 8.4 MB
  float* P = (float*)carve((size_t)512 * 32768 * 4);        // 67.1 MB
  float* Q = (float*)carve((size_t)2 * 8 * 3 * 16384 * 4);  // 3.1 MB
  float* scalars = (float*)carve(256);  // [0]=sumsq(A), [1]=sumsq(A^2)
  float* AR = (float*)carve(256 * 256 * 4);
  float* AI = (float*)carve(256 * 256 * 4);
  float* XR = (float*)carve(256 * 256 * 4);
  float* XI = (float*)carve(256 * 256 * 4);
  float* YR = (float*)carve(256 * 256 * 4);
  float* YI = (float*)carve(256 * 256 * 4);
  float* ZR = (float*)carve(256 * 256 * 4);
  float* ZI = (float*)carve(256 * 256 * 4);

  k_mlp<<<(total + 255) / 256, 256, 0, stream>>>(
      x1, x0, W1, b1, W2, b2, W3, b3, hz, B, scalars, (float*)d_out);
  k_gemm_f<<<512, 512, 0, stream>>>(hz, P);
  k_reduce1<<<dim3(128, 3, 8), 128, 0, stream>>>(P, Q);
  k_reduce2<<<dim3(128, 3), 128, 0, stream>>>(Q, AR, AI, scalars,
                                              1.0f / (256.0f * (float)B));

  // NS schedule (R9-calibrated, absmax 1.22e-4 vs 3.32e-4 threshold; err
  // model ~9.4/M^2 with M=278 — do NOT shorten):
  // 1x clamp(1.5-NS, rescaled, raw-A norm-folded) + 6x (2x - x^3)
  // + 4x (1.5-NS); trace fused into the last update. Triangular grids
  // (136 blocks): Hermitian iterates, mirror conj-transpose writes.
  const int NIT = 11;
  float *cR = AR, *cI = AI, *nR = XR, *nI = XI;
  for (int it = 0; it < NIT; it++) {
    int mode = (it == 0) ? 0 : (it <= 6 ? 1 : 2);
    int fin = (it == NIT - 1) ? 1 : 0;
    k_csq<<<136, 1024, 0, stream>>>(cR, cI, YR, YI, scalars + 1, it == 0);
    k_cupd<<<136, 1024, 0, stream>>>(cR, cI, YR, YI, nR, nI, scalars, mode, AR,
                                     AI, (float*)d_out, fin);
    if (it == 0) {
      cR = XR; cI = XI; nR = ZR; nI = ZI;
    } else {
      std::swap(cR, nR);
      std::swap(cI, nI);
    }
  }
}

// Round 16
// 219.072 us; speedup vs baseline: 1.1952x; 1.1952x over previous
//
#include <hip/hip_runtime.h>
#include <cstdint>
#include <cstddef>
#include <utility>

#define PI_F 3.14159265358979323846f

typedef __attribute__((ext_vector_type(8))) _Float16 half8;
typedef __attribute__((ext_vector_type(4))) float f32x4;

struct U4 { unsigned int w[4]; };

static __device__ __forceinline__ unsigned int packhalf2(float c, float s) {
  _Float16 hc = (_Float16)c, hs = (_Float16)s;
  unsigned short uc = __builtin_bit_cast(unsigned short, hc);
  unsigned short us = __builtin_bit_cast(unsigned short, hs);
  return (unsigned int)uc | ((unsigned int)us << 16);
}

// ---------------------------------------------------------------------------
// K1: MLP for all 2B samples -> hz[sample][16] = {h[0..7], z[0..6], 0}.
// Block 0 thread 0 also zero-inits scalars + out.
// ---------------------------------------------------------------------------
__global__ __launch_bounds__(256) void k_mlp(
    const float* __restrict__ x1, const float* __restrict__ x0,
    const float* __restrict__ W1, const float* __restrict__ b1,
    const float* __restrict__ W2, const float* __restrict__ b2,
    const float* __restrict__ W3, const float* __restrict__ b3,
    float* __restrict__ hz, int B, float* __restrict__ scalars,
    float* __restrict__ out) {
  int s = blockIdx.x * blockDim.x + threadIdx.x;
  if (blockIdx.x == 0 && threadIdx.x == 0) {
    scalars[0] = 0.f;
    scalars[1] = 0.f;
    out[0] = 0.f;
  }
  if (s >= 2 * B) return;
  const float* xp = (s < B) ? (x1 + (size_t)s * 8) : (x0 + (size_t)(s - B) * 8);
  float x[8];
#pragma unroll
  for (int k = 0; k < 8; k++) x[k] = xp[k];
  float a1[10];
#pragma unroll
  for (int o = 0; o < 10; o++) {
    float v = b1[o];
#pragma unroll
    for (int k = 0; k < 8; k++) v = fmaf(W1[o * 8 + k], x[k], v);
    a1[o] = fmaxf(v, 0.f);
  }
  float a2[10];
#pragma unroll
  for (int o = 0; o < 10; o++) {
    float v = b2[o];
#pragma unroll
    for (int k = 0; k < 10; k++) v = fmaf(W2[o * 10 + k], a1[k], v);
    a2[o] = fmaxf(v, 0.f);
  }
  float h[8];
#pragma unroll
  for (int o = 0; o < 8; o++) {
    float v = b3[o];
#pragma unroll
    for (int k = 0; k < 10; k++) v = fmaf(W3[o * 10 + k], a2[k], v);
    h[o] = v;
  }
  float outv[16];
#pragma unroll
  for (int k = 0; k < 8; k++) outv[k] = h[k];
#pragma unroll
  for (int k = 0; k < 7; k++) outv[8 + k] = (PI_F - h[k]) * (PI_F - h[k + 1]);
  outv[15] = 0.f;
  float4* dst = (float4*)(hz + (size_t)s * 16);
#pragma unroll
  for (int q = 0; q < 4; q++) dst[q] = ((float4*)outv)[q];
}

// ---------------------------------------------------------------------------
// K3: FUSED gen+GEMM (R14-proven form — do NOT interleave gen between MFMA
// clusters: MFMA blocks its own wave, so intra-wave weaving cannot overlap
// pipes and the extra live state cost VGPR/occupancy, R15 -47%). 512 blocks
// x 512 threads. Each block computes one 128x128 quadrant over a private
// K-slab; the fp16 (cos,sin) chunk for kb it+1 is GENERATED IN-LDS
// (Gray-code walk + HW v_sin/v_cos) while other waves/blocks MFMA chunk it
// (cross-wave overlap, m114) — no Ach array, no global staging.
//   b in [0,128):   qt0 (0:128,0:128)    diag, kbPer=32, jj walk [0,16)
//   b in [128,384): qt1 (0:128,128:256)  off,  kbPer=16, jj walk [0,32)
//   b in [384,512): qt2 (128:256,128:256)diag, kbPer=32, jj walk [16,32)
// Partials P[b][plane][128][128] f32 (67 MB).
// ---------------------------------------------------------------------------
__global__ __launch_bounds__(512) void k_gemm_f(const float* __restrict__ hz,
                                                float* __restrict__ P) {
  __shared__ _Float16 lds[2][16384];  // 2 x 32 KB chunk buffers
  __shared__ float hzb[2][32][17];    // double-buffered hz rows (padded)
  int b = blockIdx.x;
  int qt = (b < 128) ? 0 : (b < 384 ? 1 : 2);
  int z = b - ((qt == 0) ? 0 : (qt == 1) ? 128 : 384);
  int kbPer = (qt == 1) ? 16 : 32;
  int kb0 = z * kbPer;
  int rowLocalBase = (qt == 2) ? 128 : 0;  // global row - local row
  int bRowBase = (qt == 1) ? 128 : 0;      // B-operand local row base
  int t = threadIdx.x, wave = t >> 6, lane = t & 63;
  unsigned int reMask = (kb0 < 2048) ? 0u : 0x80008000u;
  unsigned int imMask = (kb0 < 2048) ? 0x80000000u : 0x00008000u;

  int s = t & 31, octH = t >> 5;
  int oct = octH & 7, jHalf = octH >> 3;
  const int nJ = (qt == 1) ? 16 : 8;
  const int jj0 = (qt == 1) ? jHalf * 16 : ((qt == 2) ? 16 : 0) + jHalf * 8;
  const int halfoff = (2 * s) ^ (oct << 3);
  const float S5 = (oct & 4) ? -1.f : 1.f;
  const float S6 = (oct & 2) ? -1.f : 1.f;
  const float S7 = (oct & 1) ? -1.f : 1.f;

  auto loadHz = [&](int kb) {
    if (t < 128) {
      int smp = t >> 2, q = t & 3;
      const float4 v =
          *(const float4*)(hz + (size_t)(kb * 32 + smp) * 16 + q * 4);
      float* d = &hzb[kb & 1][smp][q * 4];
      d[0] = v.x;
      d[1] = v.y;
      d[2] = v.z;
      d[3] = v.w;
    }
  };

  // generate chunk kb into lds[buf] (reads hzb[kb&1], loaded last iter)
  auto gen = [&](int kb, int buf) {
    int hb = kb & 1;
    float h[8], z7[7];
#pragma unroll
    for (int k = 0; k < 8; k++) h[k] = hzb[hb][s][k];
#pragma unroll
    for (int k = 0; k < 7; k++) z7[k] = hzb[hb][s][8 + k];
    int g0 = jj0 ^ (jj0 >> 1);
    float sg[5];
#pragma unroll
    for (int w = 0; w < 5; w++) sg[w] = ((g0 >> (4 - w)) & 1) ? -1.f : 1.f;
    float phi = sg[0] * h[0] + sg[1] * h[1] + sg[2] * h[2] + sg[3] * h[3] +
                sg[4] * h[4] + S5 * h[5] + S6 * h[6] + S7 * h[7] +
                sg[0] * sg[1] * z7[0] + sg[1] * sg[2] * z7[1] +
                sg[2] * sg[3] * z7[2] + sg[3] * sg[4] * z7[3] +
                sg[4] * S5 * z7[4] + S5 * S6 * z7[5] + S6 * S7 * z7[6];
    int g = g0;
    auto emitRow = [&](int gg, float ph) {
      int lr = gg * 8 + oct - rowLocalBase;  // local row in chunk
      float r = ph * 0.07957747154594767f;   // ph/(4*pi) revolutions
      r = r - floorf(r);
      float sv = __builtin_amdgcn_sinf(r);
      float cv = __builtin_amdgcn_cosf(r);
      *(unsigned int*)&lds[buf][lr * 64 + halfoff] = packhalf2(cv, sv);
    };
    emitRow(g, phi);
#pragma unroll
    for (int stp = 1; stp < 16; stp++) {
      if (stp >= nJ) break;  // nJ is 8 or 16; unroll fully, break for diag
      const int bbit = __builtin_ctz(stp);  // == ctz(jj0+stp): jj0 % nJ == 0
      const int w = 4 - bbit;
      float nbl = (w == 0) ? 0.f : sg[w - 1] * z7[w - 1];
      float nbr = (w == 4) ? S5 * z7[4] : sg[w + 1] * z7[w];
      phi -= 2.f * sg[w] * (h[w] + nbl + nbr);
      sg[w] = -sg[w];
      g ^= (1 << bbit);
      emitRow(g, phi);
    }
  };

  f32x4 accR[2][4] = {};
  f32x4 accI[2][4] = {};

  // prologue: hz(kb0) -> gen chunk(kb0) -> hz(kb0+1)
  loadHz(kb0);
  __syncthreads();
  gen(kb0, 0);
  loadHz(kb0 + 1);
  __syncthreads();

  for (int it = 0; it < kbPer; ++it) {
    // generate next chunk into the other buffer; prefetch hz two ahead
    if (it + 1 < kbPer) {
      gen(kb0 + it + 1, (it + 1) & 1);
      if (it + 2 < kbPer) loadHz(kb0 + it + 2);
    }
    int buf = it & 1;
#pragma unroll
    for (int kk = 0; kk < 2; kk++) {
      int cb = kk * 4 + (lane >> 4);
      half8 af[2];
#pragma unroll
      for (int fr = 0; fr < 2; fr++) {
        int r = (wave >> 1) * 32 + fr * 16 + (lane & 15);
        af[fr] = *(const half8*)&lds[buf][r * 64 + ((cb ^ (r & 7)) << 3)];
      }
#pragma unroll
      for (int fc = 0; fc < 4; fc++) {
        int rb = bRowBase + (wave & 1) * 64 + fc * 16 + (lane & 15);
        half8 bv = *(const half8*)&lds[buf][rb * 64 + ((cb ^ (rb & 7)) << 3)];
        U4 u = __builtin_bit_cast(U4, bv), ur, ui;
#pragma unroll
        for (int q = 0; q < 4; q++) {
          unsigned int xv = u.w[q];
          ur.w[q] = xv ^ reMask;
          ui.w[q] = ((xv << 16) | (xv >> 16)) ^ imMask;
        }
        half8 bfr = __builtin_bit_cast(half8, ur);
        half8 bfi = __builtin_bit_cast(half8, ui);
#pragma unroll
        for (int fr = 0; fr < 2; fr++) {
          accR[fr][fc] = __builtin_amdgcn_mfma_f32_16x16x32_f16(
              af[fr], bfr, accR[fr][fc], 0, 0, 0);
          accI[fr][fc] = __builtin_amdgcn_mfma_f32_16x16x32_f16(
              af[fr], bfi, accI[fr][fc], 0, 0, 0);
        }
      }
    }
    __syncthreads();  // gen(it+1) writes + MFMA(it) reads complete
  }
  float* PR = P + (size_t)b * 32768;
  float* PI = PR + 16384;
  int r4 = (lane >> 4) * 4, cj = lane & 15;
#pragma unroll
  for (int fr = 0; fr < 2; fr++)
#pragma unroll
    for (int fc = 0; fc < 4; fc++)
#pragma unroll
      for (int r = 0; r < 4; r++) {
        int li = (wave >> 1) * 32 + fr * 16 + r4 + r;
        int lj = (wave & 1) * 64 + fc * 16 + cj;
        PR[li * 128 + lj] = accR[fr][fc][r];
        PI[li * 128 + lj] = accI[fr][fc][r];
      }
}

// ---------------------------------------------------------------------------
// K4a: stage-1 reduce over slab groups. grid (128 rows, 3 qts, 8 groups).
// ---------------------------------------------------------------------------
__global__ __launch_bounds__(128) void k_reduce1(const float* __restrict__ P,
                                                 float* __restrict__ Q) {
  int r = blockIdx.x, qt = blockIdx.y, g = blockIdx.z, c = threadIdx.x;
  int nsl = (qt == 1) ? 32 : 16;
  int b0 = ((qt == 0) ? 0 : (qt == 1) ? 128 : 384) + g * nsl;
  float vR = 0.f, vI = 0.f;
  for (int u = 0; u < nsl; u++) {
    const float* base = P + (size_t)(b0 + u) * 32768 + r * 128 + c;
    vR += base[0];
    vI += base[16384];
  }
  size_t qidx = ((size_t)(g * 3 + qt) * 128 + r) * 128 + c;
  Q[qidx] = vR;
  Q[qidx + (size_t)8 * 3 * 16384] = vI;
}

// K4b: stage-2: sum 8 groups, map quadrant->global, Hermitian A + ||A||_F^2.
__global__ __launch_bounds__(128) void k_reduce2(const float* __restrict__ Q,
                                                 float* __restrict__ AR,
                                                 float* __restrict__ AI,
                                                 float* __restrict__ sumsq,
                                                 float scale) {
  int r = blockIdx.x, qt = blockIdx.y, c = threadIdx.x;
  float vR = 0.f, vI = 0.f;
#pragma unroll
  for (int g = 0; g < 8; g++) {
    size_t qidx = ((size_t)(g * 3 + qt) * 128 + r) * 128 + c;
    vR += Q[qidx];
    vI += Q[qidx + (size_t)8 * 3 * 16384];
  }
  vR *= scale;
  vI *= scale;
  int i = (qt == 2) ? 128 + r : r;
  int j = (qt == 0) ? c : 128 + c;
  float ss = 0.f;
  bool diagQ = (qt != 1);
  if (!diagQ || c > r) {
    AR[i * 256 + j] = vR;
    AR[j * 256 + i] = vR;
    AI[i * 256 + j] = vI;
    AI[j * 256 + i] = -vI;
    ss = 2.f * (vR * vR + vI * vI);
  } else if (c == r) {
    AR[i * 256 + j] = vR;
    AI[i * 256 + j] = 0.f;
    ss = vR * vR;
  }
#pragma unroll
  for (int o = 32; o > 0; o >>= 1) ss += __shfl_down(ss, o);
  __shared__ float w2[2];
  if ((c & 63) == 0) w2[c >> 6] = ss;
  __syncthreads();
  if (c == 0) atomicAdd(sumsq, w2[0] + w2[1]);
}

// ---------------------------------------------------------------------------
// Newton-Schulz complex matmuls, k-split-4, FULL 256-block grids
// (R9/R13-proven — triangular 136-block variant was a regression, R15:
// latency-bound kernels don't speed up from work reduction).
// ---------------------------------------------------------------------------
__global__ __launch_bounds__(1024) void k_csq(
    const float* __restrict__ XR, const float* __restrict__ XI,
    float* __restrict__ YR, float* __restrict__ YI,
    float* __restrict__ sumsqY, int accumNorm) {
  __shared__ float rp[16][258][2];
  __shared__ float cpT[16][258][2];
  __shared__ float pacc[3][256][2];
  __shared__ float w16[16];
  int t = threadIdx.x;
  int bi = blockIdx.x >> 4, bj = blockIdx.x & 15;
  {
    int r = t >> 6, c = (t & 63) * 4;
    const float4 vr = *(const float4*)&XR[(bi * 16 + r) * 256 + c];
    const float4 vi = *(const float4*)&XI[(bi * 16 + r) * 256 + c];
    float4 p0 = {vr.x, vi.x, vr.y, vi.y};
    float4 p1 = {vr.z, vi.z, vr.w, vi.w};
    *(float4*)&rp[r][c][0] = p0;
    *(float4*)&rp[r][c + 2][0] = p1;
    int row = t >> 2, c0 = (t & 3) * 4;
    const float4 wr = *(const float4*)&XR[row * 256 + bj * 16 + c0];
    const float4 wi = *(const float4*)&XI[row * 256 + bj * 16 + c0];
    float2 q0 = {wr.x, wi.x}, q1 = {wr.y, wi.y};
    float2 q2 = {wr.z, wi.z}, q3 = {wr.w, wi.w};
    *(float2*)&cpT[c0 + 0][row][0] = q0;
    *(float2*)&cpT[c0 + 1][row][0] = q1;
    *(float2*)&cpT[c0 + 2][row][0] = q2;
    *(float2*)&cpT[c0 + 3][row][0] = q3;
  }
  __syncthreads();
  int sub = t >> 8, tt = t & 255, ty = tt >> 4, tx = tt & 15;
  float sR = 0.f, sI = 0.f;
  int k0 = sub * 64;
#pragma unroll 8
  for (int k = k0; k < k0 + 64; k++) {
    float xr = rp[ty][k][0], xi = rp[ty][k][1];
    float yr = cpT[tx][k][0], yi = cpT[tx][k][1];
    sR = fmaf(xr, yr, sR);
    sR = fmaf(-xi, yi, sR);
    sI = fmaf(xr, yi, sI);
    sI = fmaf(xi, yr, sI);
  }
  if (sub) {
    pacc[sub - 1][tt][0] = sR;
    pacc[sub - 1][tt][1] = sI;
  }
  __syncthreads();
  float v = 0.f;
  if (sub == 0) {
    sR += (pacc[0][tt][0] + pacc[1][tt][0]) + pacc[2][tt][0];
    sI += (pacc[0][tt][1] + pacc[1][tt][1]) + pacc[2][tt][1];
    int i = bi * 16 + ty, j = bj * 16 + tx;
    YR[i * 256 + j] = sR;
    YI[i * 256 + j] = sI;
    if (accumNorm) v = sR * sR + sI * sI;
  }
#pragma unroll
  for (int o = 32; o > 0; o >>= 1) v += __shfl_down(v, o);
  if ((t & 63) == 0) w16[t >> 6] = v;
  __syncthreads();
  if (t == 0 && accumNorm)
    atomicAdd(sumsqY, (w16[0] + w16[1]) + (w16[2] + w16[3]));
}

// Z = aC*X - bC*(X@Y); same structure.
// mode 0: first iter ON RAW A (norm-folding). mode 1: 2x-x^3. mode 2: 1.5-NS.
// finalTrace: accumulate out += -0.5*sum(A .* Z) instead of writing Z.
__global__ __launch_bounds__(1024) void k_cupd(
    const float* __restrict__ XR, const float* __restrict__ XI,
    const float* __restrict__ YR, const float* __restrict__ YI,
    float* __restrict__ ZR, float* __restrict__ ZI,
    const float* __restrict__ scalars, int mode,
    const float* __restrict__ AR, const float* __restrict__ AI,
    float* __restrict__ out, int finalTrace) {
  __shared__ float rp[16][258][2];
  __shared__ float cpT[16][258][2];
  __shared__ float pacc[3][256][2];
  __shared__ float w16[16];
  int t = threadIdx.x;
  int bi = blockIdx.x >> 4, bj = blockIdx.x & 15;
  {
    int r = t >> 6, c = (t & 63) * 4;
    const float4 vr = *(const float4*)&XR[(bi * 16 + r) * 256 + c];
    const float4 vi = *(const float4*)&XI[(bi * 16 + r) * 256 + c];
    float4 p0 = {vr.x, vi.x, vr.y, vi.y};
    float4 p1 = {vr.z, vi.z, vr.w, vi.w};
    *(float4*)&rp[r][c][0] = p0;
    *(float4*)&rp[r][c + 2][0] = p1;
    int row = t >> 2, c0 = (t & 3) * 4;
    const float4 wr = *(const float4*)&YR[row * 256 + bj * 16 + c0];
    const float4 wi = *(const float4*)&YI[row * 256 + bj * 16 + c0];
    float2 q0 = {wr.x, wi.x}, q1 = {wr.y, wi.y};
    float2 q2 = {wr.z, wi.z}, q3 = {wr.w, wi.w};
    *(float2*)&cpT[c0 + 0][row][0] = q0;
    *(float2*)&cpT[c0 + 1][row][0] = q1;
    *(float2*)&cpT[c0 + 2][row][0] = q2;
    *(float2*)&cpT[c0 + 3][row][0] = q3;
  }
  __syncthreads();
  int sub = t >> 8, tt = t & 255, ty = tt >> 4, tx = tt & 15;
  float sR = 0.f, sI = 0.f;
  int k0 = sub * 64;
#pragma unroll 8
  for (int k = k0; k < k0 + 64; k++) {
    float xr = rp[ty][k][0], xi = rp[ty][k][1];
    float yr = cpT[tx][k][0], yi = cpT[tx][k][1];
    sR = fmaf(xr, yr, sR);
    sR = fmaf(-xi, yi, sR);
    sI = fmaf(xr, yi, sI);
    sI = fmaf(xi, yr, sI);
  }
  if (sub) {
    pacc[sub - 1][tt][0] = sR;
    pacc[sub - 1][tt][1] = sI;
  }
  __syncthreads();
  float v = 0.f;
  if (sub == 0) {
    sR += (pacc[0][tt][0] + pacc[1][tt][0]) + pacc[2][tt][0];
    sI += (pacc[0][tt][1] + pacc[1][tt][1]) + pacc[2][tt][1];
    float aC, bC;
    if (mode == 0) {
      float f2 = scalars[0];
      float f = sqrtf(f2);
      float Rhat = 1.41421356f * sqrtf(scalars[1]) / f2;
      float g = 1.0f / (1.75f * Rhat);
      aC = 1.5f * g / f;
      float gf = g / f;
      bC = 0.5f * gf * gf * gf;
    } else if (mode == 1) {
      aC = 2.0f;
      bC = 1.0f;
    } else {
      aC = 1.5f;
      bC = 0.5f;
    }
    int idx = (bi * 16 + ty) * 256 + bj * 16 + tx;
    float zr = aC * XR[idx] - bC * sR;
    float zi = aC * XI[idx] - bC * sI;
    if (!finalTrace) {
      ZR[idx] = zr;
      ZI[idx] = zi;
    } else {
      v = AR[idx] * zr + AI[idx] * zi;
    }
  }
#pragma unroll
  for (int o = 32; o > 0; o >>= 1) v += __shfl_down(v, o);
  if ((t & 63) == 0) w16[t >> 6] = v;
  __syncthreads();
  if (t == 0 && finalTrace)
    atomicAdd(out, -0.5f * ((w16[0] + w16[1]) + (w16[2] + w16[3])));
}

// ---------------------------------------------------------------------------
extern "C" void kernel_launch(void* const* d_in, const int* in_sizes, int n_in,
                              void* d_out, int out_size, void* d_ws,
                              size_t ws_size, hipStream_t stream) {
  const float* x1 = (const float*)d_in[0];
  const float* x0 = (const float*)d_in[1];
  const float* W1 = (const float*)d_in[2];
  const float* b1 = (const float*)d_in[3];
  const float* W2 = (const float*)d_in[4];
  const float* b2 = (const float*)d_in[5];
  const float* W3 = (const float*)d_in[6];
  const float* b3 = (const float*)d_in[7];
  (void)n_in;
  (void)out_size;
  (void)ws_size;

  const int B = in_sizes[0] / 8;  // 65536
  const int total = 2 * B;        // 131072

  char* ws = (char*)d_ws;
  size_t off = 0;
  auto carve = [&](size_t bytes) -> void* {
    off = (off + 255) & ~(size_t)255;
    void* p = ws + off;
    off += bytes;
    return p;
  };
  float* hz = (float*)carve((size_t)total * 16 * 4);        // 8.4 MB
  float* P = (float*)carve((size_t)512 * 32768 * 4);        // 67.1 MB
  float* Q = (float*)carve((size_t)2 * 8 * 3 * 16384 * 4);  // 3.1 MB
  float* scalars = (float*)carve(256);  // [0]=sumsq(A), [1]=sumsq(A^2)
  float* AR = (float*)carve(256 * 256 * 4);
  float* AI = (float*)carve(256 * 256 * 4);
  float* XR = (float*)carve(256 * 256 * 4);
  float* XI = (float*)carve(256 * 256 * 4);
  float* YR = (float*)carve(256 * 256 * 4);
  float* YI = (float*)carve(256 * 256 * 4);
  float* ZR = (float*)carve(256 * 256 * 4);
  float* ZI = (float*)carve(256 * 256 * 4);

  k_mlp<<<(total + 255) / 256, 256, 0, stream>>>(
      x1, x0, W1, b1, W2, b2, W3, b3, hz, B, scalars, (float*)d_out);
  k_gemm_f<<<512, 512, 0, stream>>>(hz, P);
  k_reduce1<<<dim3(128, 3, 8), 128, 0, stream>>>(P, Q);
  k_reduce2<<<dim3(128, 3), 128, 0, stream>>>(Q, AR, AI, scalars,
                                              1.0f / (256.0f * (float)B));

  // NS schedule (R9-calibrated, absmax 1.22e-4 vs 3.32e-4 threshold; err
  // model ~9.4/M^2 with M=278 — do NOT shorten):
  // 1x clamp(1.5-NS, rescaled, raw-A norm-folded) + 6x (2x - x^3)
  // + 4x (1.5-NS); trace fused into the last update. Multi-dispatch chain
  // (~5-6 us/launch) beats any gfx950 grid-sync (>=20 us, R10/R11).
  const int NIT = 11;
  float *cR = AR, *cI = AI, *nR = XR, *nI = XI;
  for (int it = 0; it < NIT; it++) {
    int mode = (it == 0) ? 0 : (it <= 6 ? 1 : 2);
    int fin = (it == NIT - 1) ? 1 : 0;
    k_csq<<<256, 1024, 0, stream>>>(cR, cI, YR, YI, scalars + 1, it == 0);
    k_cupd<<<256, 1024, 0, stream>>>(cR, cI, YR, YI, nR, nI, scalars, mode, AR,
                                     AI, (float*)d_out, fin);
    if (it == 0) {
      cR = XR; cI = XI; nR = ZR; nI = ZI;
    } else {
      std::swap(cR, nR);
      std::swap(cI, nI);
    }
  }
}